// Round 19
// baseline (1226.522 us; speedup 1.0000x reference)
//
#include <hip/hip_runtime.h>

#define SEQ   1024
#define BATCH 512
#define HID   128

typedef __attribute__((ext_vector_type(8))) short          short8v;
typedef __attribute__((ext_vector_type(4))) float          float4v;
typedef __attribute__((ext_vector_type(4))) unsigned short ushort4v;

__device__ __forceinline__ unsigned short f2bf(float f) {
    union { float f; unsigned u; } v; v.f = f;
    return (unsigned short)((v.u + 0x7fffu + ((v.u >> 16) & 1u)) >> 16);
}
__device__ __forceinline__ float bf2f(unsigned short u) {
    union { unsigned u; float f; } v; v.u = ((unsigned)u) << 16;
    return v.f;
}
__device__ __forceinline__ unsigned packbf(float a, float b) {
    return (unsigned)f2bf(a) | ((unsigned)f2bf(b) << 16);
}
__device__ __forceinline__ float fast_cos(float x) {
    return __builtin_amdgcn_cosf(x * 0.15915494309189535f);   // v_cos takes revolutions
}
__device__ __forceinline__ float fast_sigmoid(float x) {
    return __builtin_amdgcn_rcpf(1.0f + __builtin_amdgcn_exp2f(-1.4426950408889634f * x));
}
__device__ __forceinline__ float fast_tanh(float x) {
    return 1.0f - 2.0f * __builtin_amdgcn_rcpf(1.0f + __builtin_amdgcn_exp2f(2.8853900817779268f * x));
}
template<int CTRL, int RM>
__device__ __forceinline__ float dpp1(float v) {
    union { float f; int i; } s, o, r;
    s.f = v; o.f = 1.0f;
    r.i = __builtin_amdgcn_update_dpp(o.i, s.i, CTRL, RM, 0xf, false);
    return r.f;
}
#define BAR() do { asm volatile("s_waitcnt lgkmcnt(0)" ::: "memory");  \
                   __builtin_amdgcn_s_barrier();                       \
                   __builtin_amdgcn_sched_barrier(0); } while (0)

// zring swizzle (R13-verified form, 8 slots): bijective in col.
__device__ __forceinline__ int zswz(int slot, int g, int c) {
    return slot * 512 + g * 128 + (c ^ ((c >> 5) << 4) ^ ((slot & 2) << 3));
}

// ---------------------------------------------------------------------------
// ONE persistent kernel. 256 WGs x 512 thr (8 waves, 2/SIMD), 2 rows/WG.
// NEW decomposition: wave w owns cols [w*16, w*16+16) of ALL FOUR gates
// (MFMA tiles = gates). Each lane (l15,kg) then holds f/i/g/o preacts for
// col w*16+l15, rows 0/1 (reg parity) -> activation AND cell update are
// LANE-LOCAL. No gact array. Only cross-wave datum: f-cumprod segment
// totals (scanW[8][2], one scalar/wave/row).
// Phase A: 16-MFMA h-GEMM (rows replicated in M) + one XTILE (gate t&3 of
//   next 4-step window; x-weights parked in LDS, R18-verified) + z-add +
//   lane-local activations + in-wave 4-DPP f-scan + scanW publish. S1.
// Phase B (all lanes): 7-mul predicated cross-wave prefix + cell update +
//   h_bf/out writes (kg==0); waves 4-7 also publish staged x (w==2). S2.
// ---------------------------------------------------------------------------
__global__ __launch_bounds__(512, 1) void qlstm_fused(
    const float* __restrict__ X,
    const float* __restrict__ Wf, const float* __restrict__ bfp,
    const float* __restrict__ Wi, const float* __restrict__ bip,
    const float* __restrict__ Wg, const float* __restrict__ bgp,
    const float* __restrict__ Wo, const float* __restrict__ bop,
    float* __restrict__ out)
{
    __shared__ short8v  wx_lds[8][4][4][64];                 // 128 KB x-weight frags
    __shared__ unsigned zr_lds[8 * 4 * 128];                 // 16 KB bf16 row-pair z ring
    __shared__ alignas(8)  unsigned short h_bf[2][HID];      // 512 B
    __shared__ alignas(16) unsigned short x_win[2][8][HID];  // 4 KB x window dbuf
    __shared__ float scanW[8][2];                            // f segment totals

    const int tid = threadIdx.x, lane = tid & 63, wid = tid >> 6;
    const int l15 = lane & 15, kg = lane >> 4;
    const int b0 = blockIdx.x * 2;
    const int col = wid * 16 + l15;          // this lane's column (per gate)

    // ---- prologue A: x-weight frags -> LDS (per wave: 4 gates x 4 ks) ----
    #pragma unroll
    for (int g2 = 0; g2 < 4; ++g2) {
        const float* Wsel = (g2 == 0) ? Wf : (g2 == 1) ? Wi : (g2 == 2) ? Wg : Wo;
        #pragma unroll
        for (int ks = 0; ks < 4; ++ks) {
            short8v wx;
            #pragma unroll
            for (int j = 0; j < 8; ++j)
                wx[j] = (short)f2bf(Wsel[(size_t)(ks * 32 + kg * 8 + j) * HID + col]);
            wx_lds[wid][g2][ks][lane] = wx;
        }
    }
    BAR();   // retire wx regs

    // ---- prologue B: h-weight frags in regs (4 gates x 4 ks = 64 VGPR) ----
    short8v bwh[4][4];
    float biasr[4];
    #pragma unroll
    for (int g2 = 0; g2 < 4; ++g2) {
        const float* Wsel = (g2 == 0) ? Wf : (g2 == 1) ? Wi : (g2 == 2) ? Wg : Wo;
        const float* bsel = (g2 == 0) ? bfp : (g2 == 1) ? bip : (g2 == 2) ? bgp : bop;
        #pragma unroll
        for (int ks = 0; ks < 4; ++ks) {
            short8v wh;
            #pragma unroll
            for (int j = 0; j < 8; ++j)
                wh[j] = (short)f2bf(Wsel[(size_t)(128 + ks * 32 + kg * 8 + j) * HID + col]);
            bwh[g2][ks] = wh;
        }
        biasr[g2] = bsel[col];
    }

    if (tid < 128) ((unsigned*)h_bf)[tid] = 0u;   // h0 = 0

    float c_r0 = 0.f, c_r1 = 0.f, hL0 = 0.f, hL1 = 0.f;   // c0 = 0; lane-local cell

    // x staging geometry (waves 4-7; pt 0..255): 1 float4/lane  (R18 verbatim)
    const int pt = tid - 256;
    const int sm = (pt >> 5) & 7;            // window row m = 2*step+brow
    const int sc = pt & 31;                  // 4-float chunk
    const size_t xrow_off = ((size_t)(b0 + (sm & 1))) * HID + sc * 4;
    const int xw_boff = sm * 256 + ((((sc >> 1) ^ (sm & 7)) << 4) | ((sc & 1) << 3));

#define STAGE_XWIN(buf, s0) do {                                                    \
    const float* xp_ = X + ((size_t)((s0) + (sm >> 1)) * BATCH) * HID + xrow_off;   \
    float4v a_ = *(const float4v*)xp_;                                              \
    ushort4v o_;                                                                    \
    o_[0] = f2bf(a_[0]); o_[1] = f2bf(a_[1]); o_[2] = f2bf(a_[2]); o_[3] = f2bf(a_[3]); \
    *(ushort4v*)((char*)&x_win[buf][0][0] + xw_boff) = o_;                          \
} while (0)

// XTILE(G, bn, buf): 4-MFMA x-tile for gate G, cols [wid*16,+16), window at bn.
// A = x rows (8 M-slots = 4 steps x 2 rows, m>=8 replicate) from x_win[buf];
// B = wx frags from wx_lds. D reg j of lane(kg,l15): step kg*2+(j>>1), row j&1
// (valid kg<2). Writes bf16 row-pairs into zring. (R18-verified machinery.)
#define XTILE(G, bn, buf) do {                                                      \
    float4v xa_;                                                                    \
    xa_[0] = biasr[G]; xa_[1] = biasr[G]; xa_[2] = biasr[G]; xa_[3] = biasr[G];     \
    _Pragma("unroll")                                                               \
    for (int ks_ = 0; ks_ < 4; ++ks_) {                                             \
        short8v axk = *(const short8v*)((const char*)&x_win[buf][0][0] +            \
            ((l15 & 7) * 256 + (((ks_ * 4 + kg) ^ (l15 & 7)) << 4)));               \
        xa_ = __builtin_amdgcn_mfma_f32_16x16x32_bf16(axk, wx_lds[wid][G][ks_][lane], xa_, 0, 0, 0); \
    }                                                                               \
    if (kg < 2) {                                                                   \
        zr_lds[zswz(((bn) + kg * 2) & 7,     G, col)] = packbf(xa_[0], xa_[1]);     \
        zr_lds[zswz(((bn) + kg * 2 + 1) & 7, G, col)] = packbf(xa_[2], xa_[3]);     \
    }                                                                               \
} while (0)

    // ---- prologue C: stage x_win[0]<-x[0..3], x_win[1]<-x[4..7] ----
    if (wid >= 4) { STAGE_XWIN(0, 0); STAGE_XWIN(1, 4); }
    BAR();
    // ---- prologue D: produce zring window 0 (slots 0-3), all 4 gates ----
    XTILE(0, 0, 0);
    XTILE(1, 0, 0);
    XTILE(2, 0, 0);
    XTILE(3, 0, 0);
    BAR();

    float4v xg = {};   // staged x (waves 4-7; issued w==0, published w==2)

    #pragma unroll 1
    for (int t = 0; t < SEQ; ++t) {
        const int w = t & 3;
        const int W = t >> 2;
        const int bnext = (t & ~3) + 4;

        // ---------------- Phase A (all 8 waves) ----------------
        unsigned zp[4];
        #pragma unroll
        for (int g2 = 0; g2 < 4; ++g2)
            zp[g2] = zr_lds[zswz(t & 7, g2, col)];        // early z reads
        short8v ah[4];
        #pragma unroll
        for (int ks = 0; ks < 4; ++ks)
            ah[ks] = *(const short8v*)&h_bf[l15 & 1][ks * 32 + kg * 8];

        if (w == 0 && wid >= 4 && bnext + 4 < SEQ)
            xg = *(const float4v*)(X + ((size_t)(bnext + 4 + (sm >> 1)) * BATCH) * HID + xrow_off);

        // h-GEMM: 16 MFMA, tiles = gates (f first so its act/scan can start early)
        float4v acc[4];
        #pragma unroll
        for (int g2 = 0; g2 < 4; ++g2)
            #pragma unroll
            for (int j = 0; j < 4; ++j) acc[g2][j] = 0.f;
        __builtin_amdgcn_s_setprio(1);
        #pragma unroll
        for (int g2 = 0; g2 < 4; ++g2)
            #pragma unroll
            for (int ks = 0; ks < 4; ++ks)
                acc[g2] = __builtin_amdgcn_mfma_f32_16x16x32_bf16(ah[ks], bwh[g2][ks], acc[g2], 0, 0, 0);
        __builtin_amdgcn_s_setprio(0);

        // one x-tile (gate = w) of next window
        if (bnext < SEQ) {
            const int xbuf = (W + 1) & 1;
            switch (w) {
                case 0: XTILE(0, bnext, xbuf); break;
                case 1: XTILE(1, bnext, xbuf); break;
                case 2: XTILE(2, bnext, xbuf); break;
                default: XTILE(3, bnext, xbuf); break;
            }
        }

        // lane-local preacts: gate g2, rows 0/1 = regs 0/1
        const float fc0 = fast_cos(acc[0][0] + bf2f((unsigned short)(zp[0] & 0xffffu)));
        const float fc1 = fast_cos(acc[0][1] + bf2f((unsigned short)(zp[0] >> 16)));
        const float iv0 = (fast_cos(acc[1][0] + bf2f((unsigned short)(zp[1] & 0xffffu))) + 1.f) * 0.5f;
        const float iv1 = (fast_cos(acc[1][1] + bf2f((unsigned short)(zp[1] >> 16))) + 1.f) * 0.5f;
        const float gv0 = fast_tanh(acc[2][0] + bf2f((unsigned short)(zp[2] & 0xffffu)));
        const float gv1 = fast_tanh(acc[2][1] + bf2f((unsigned short)(zp[2] >> 16)));
        const float ov0 = fast_sigmoid(acc[3][0] + bf2f((unsigned short)(zp[3] & 0xffffu)));
        const float ov1 = fast_sigmoid(acc[3][1] + bf2f((unsigned short)(zp[3] >> 16)));

        // in-wave inclusive f-scan over the wave's 16 cols (l15 order; kg replicas)
        float S0 = fc0, S1 = fc1;
        S0 *= dpp1<0x111, 0xf>(S0);  S1 *= dpp1<0x111, 0xf>(S1);   // row_shr:1
        S0 *= dpp1<0x112, 0xf>(S0);  S1 *= dpp1<0x112, 0xf>(S1);   // row_shr:2
        S0 *= dpp1<0x114, 0xf>(S0);  S1 *= dpp1<0x114, 0xf>(S1);   // row_shr:4
        S0 *= dpp1<0x118, 0xf>(S0);  S1 *= dpp1<0x118, 0xf>(S1);   // row_shr:8
        if (lane == 15) { scanW[wid][0] = S0; scanW[wid][1] = S1; }

        BAR();  // S1: scanW + zring tile published

        // ---------------- Phase B (all lanes; cell is lane-local) ----------------
        float p0 = 1.f, p1 = 1.f;
        #pragma unroll
        for (int jw = 0; jw < 8; ++jw) {
            const float a = scanW[jw][0], b = scanW[jw][1];
            p0 *= (jw < wid) ? a : 1.f;
            p1 *= (jw < wid) ? b : 1.f;
        }
        const float f0 = (p0 * S0 + 1.f) * 0.5f;   // inclusive cumprod -> f
        const float f1 = (p1 * S1 + 1.f) * 0.5f;

        const float cn0 = fmaf(f0, c_r0, iv0 * gv0);
        const float cn1 = fmaf(f1, c_r1, iv1 * gv1);
        const float hn0 = ov0 * fast_tanh(cn0);
        const float hn1 = ov1 * fast_tanh(cn1);
        c_r0 = cn0; c_r1 = cn1; hL0 = hn0; hL1 = hn1;

        if (kg == 0) {
            h_bf[0][col] = f2bf(hn0);
            h_bf[1][col] = f2bf(hn1);
            out[((size_t)t * BATCH + b0) * HID + col] = hn0;
            out[((size_t)t * BATCH + b0 + 1) * HID + col] = hn1;
        }
        if (wid >= 4 && w == 2 && bnext + 4 < SEQ) {
            // publish staged x (issued w==0) for window W+2 into buf W&1
            ushort4v o_;
            o_[0] = f2bf(xg[0]); o_[1] = f2bf(xg[1]); o_[2] = f2bf(xg[2]); o_[3] = f2bf(xg[3]);
            *(ushort4v*)((char*)&x_win[W & 1][0][0] + xw_boff) = o_;
        }
        BAR();  // S2: h_bf (and x_win) ready
    }

    // final hx/cx tails (kg==0 lanes hold their column's last-step values)
    if (kg == 0) {
        const size_t base = (size_t)SEQ * BATCH * HID;
        out[base + (size_t)b0 * HID + col]       = hL0;
        out[base + (size_t)(b0 + 1) * HID + col] = hL1;
        out[base + (size_t)BATCH * HID + (size_t)b0 * HID + col]       = c_r0;
        out[base + (size_t)BATCH * HID + (size_t)(b0 + 1) * HID + col] = c_r1;
    }
#undef STAGE_XWIN
#undef XTILE
}

// ---------------------------------------------------------------------------
extern "C" void kernel_launch(void* const* d_in, const int* in_sizes, int n_in,
                              void* d_out, int out_size, void* d_ws, size_t ws_size,
                              hipStream_t stream) {
    const float* X  = (const float*)d_in[0];
    const float* Wf = (const float*)d_in[1];
    const float* bf = (const float*)d_in[2];
    const float* Wi = (const float*)d_in[3];
    const float* bi = (const float*)d_in[4];
    const float* Wg = (const float*)d_in[5];
    const float* bg = (const float*)d_in[6];
    const float* Wo = (const float*)d_in[7];
    const float* bo = (const float*)d_in[8];
    float* out = (float*)d_out;
    (void)d_ws; (void)ws_size;

    qlstm_fused<<<BATCH / 2, 512, 0, stream>>>(
        X, Wf, bf, Wi, bi, Wg, bg, Wo, bo, out);
}

// Round 20
// 1194.132 us; speedup vs baseline: 1.0271x; 1.0271x over previous
//
#include <hip/hip_runtime.h>

#define SEQ   1024
#define BATCH 512
#define HID   128

typedef __attribute__((ext_vector_type(8))) short          short8v;
typedef __attribute__((ext_vector_type(4))) float          float4v;
typedef __attribute__((ext_vector_type(4))) unsigned short ushort4v;

__device__ __forceinline__ unsigned short f2bf(float f) {
    union { float f; unsigned u; } v; v.f = f;
    return (unsigned short)((v.u + 0x7fffu + ((v.u >> 16) & 1u)) >> 16);
}
__device__ __forceinline__ float bf2f(unsigned short u) {
    union { unsigned u; float f; } v; v.u = ((unsigned)u) << 16;
    return v.f;
}
__device__ __forceinline__ unsigned packbf(float a, float b) {
    return (unsigned)f2bf(a) | ((unsigned)f2bf(b) << 16);
}
__device__ __forceinline__ float fast_cos(float x) {
    return __builtin_amdgcn_cosf(x * 0.15915494309189535f);   // v_cos takes revolutions
}
__device__ __forceinline__ float fast_sigmoid(float x) {
    return __builtin_amdgcn_rcpf(1.0f + __builtin_amdgcn_exp2f(-1.4426950408889634f * x));
}
__device__ __forceinline__ float fast_tanh(float x) {
    return 1.0f - 2.0f * __builtin_amdgcn_rcpf(1.0f + __builtin_amdgcn_exp2f(2.8853900817779268f * x));
}
template<int CTRL, int RM>
__device__ __forceinline__ float dpp1(float v) {
    union { float f; int i; } s, o, r;
    s.f = v; o.f = 1.0f;
    r.i = __builtin_amdgcn_update_dpp(o.i, s.i, CTRL, RM, 0xf, false);
    return r.f;
}
#define BAR() do { asm volatile("s_waitcnt lgkmcnt(0)" ::: "memory");  \
                   __builtin_amdgcn_s_barrier();                       \
                   __builtin_amdgcn_sched_barrier(0); } while (0)

// zring swizzle (R13-verified form, 8 slots): bijective in col.
__device__ __forceinline__ int zswz(int slot, int g, int c) {
    return slot * 512 + g * 128 + (c ^ ((c >> 5) << 4) ^ ((slot & 2) << 3));
}
__device__ __forceinline__ int gswz(int row, int g, int c) {
    return row * 512 + g * 128 + (c ^ ((c >> 5) << 4));
}

// ---------------------------------------------------------------------------
// ONE persistent kernel. 256 WGs x 512 thr (8 waves, 2/SIMD), 2 rows/WG.
// R18 structure with ONE change: the XTILE x-GEMM moves from Phase A (all
// waves, on the critical chain) to Phase B on waves 4-7 (which were idle
// there), overlapping the cell update on waves 0-3. Its ax-read bank
// conflicts leave the serial chain.
// Wave w = (gate g=w>>1, col-half hb=w&1) for the h-GEMM/activation.
// Phase A (all 8 waves): 16-MFMA h-GEMM (rows replicated in M) + z-add from
//   zring + activation of 1 col x 2 rows/lane (f-waves: DPP scan + scanT).
//   Waves 4-7 additionally issue the w==0 global x load.  S1.
// Phase B: waves 0-3 = cell update (1 (row,col)/lane, scanT fixup for
//   cols>=64); waves 4-7 = gate (wid-4)'s TWO XTILE units (both halves,
//   shared ax frags) writing next window's zring + w==2 x_win publish.  S2.
// Ring safety: window W+1 slots written Phase B, window W slots read Phase A
// (exact mod-8 partition); slot bnext's last write (step bnext-1, Phase B)
// and first read (step bnext, Phase A) separated by S2's lgkm drain.
// ---------------------------------------------------------------------------
__global__ __launch_bounds__(512, 1) void qlstm_fused(
    const float* __restrict__ X,
    const float* __restrict__ Wf, const float* __restrict__ bfp,
    const float* __restrict__ Wi, const float* __restrict__ bip,
    const float* __restrict__ Wg, const float* __restrict__ bgp,
    const float* __restrict__ Wo, const float* __restrict__ bop,
    float* __restrict__ out)
{
    __shared__ short8v  wx_lds[8][4][4][64];                 // 128 KB x-weight frags
    __shared__ unsigned zr_lds[8 * 4 * 128];                 // 16 KB bf16 row-pair z ring
    __shared__ float    ga_lds[2 * 4 * 128];                 // 4 KB activated gates
    __shared__ float    bias_lds[4 * 128];                   // 2 KB bias per gate/col
    __shared__ alignas(8)  unsigned short h_bf[2][HID];      // 512 B
    __shared__ alignas(16) unsigned short x_win[2][8][HID];  // 4 KB x window dbuf
    __shared__ float scanT[2];                               // f half-totals per row

    const int tid = threadIdx.x, lane = tid & 63, wid = tid >> 6;
    const int l15 = lane & 15, kg = lane >> 4;
    const int b0 = blockIdx.x * 2;
    const int g  = wid >> 1;                 // gate 0..3 (h-GEMM role)
    const int hb = wid & 1;                  // col-half
    const int cb = hb * 64;
    const float* Wsel = (g == 0) ? Wf : (g == 1) ? Wi : (g == 2) ? Wg : Wo;
    const float* bsel = (g == 0) ? bfp : (g == 1) ? bip : (g == 2) ? bgp : bop;

    // ---- prologue A: x-weight frags -> LDS (transient regs, retire at BAR) ----
    #pragma unroll
    for (int n = 0; n < 4; ++n) {
        const int col = cb + n * 16 + l15;
        #pragma unroll
        for (int ks = 0; ks < 4; ++ks) {
            short8v wx;
            #pragma unroll
            for (int j = 0; j < 8; ++j)
                wx[j] = (short)f2bf(Wsel[(size_t)(ks * 32 + kg * 8 + j) * HID + col]);
            wx_lds[wid][n][ks][lane] = wx;
        }
    }
    BAR();   // retire wx regs

    // ---- prologue B: h-weight frags in regs (64 VGPR); bias -> LDS ----
    short8v bwh[4][4];
    #pragma unroll
    for (int n = 0; n < 4; ++n) {
        const int col = cb + n * 16 + l15;
        #pragma unroll
        for (int ks = 0; ks < 4; ++ks) {
            short8v wh;
            #pragma unroll
            for (int j = 0; j < 8; ++j)
                wh[j] = (short)f2bf(Wsel[(size_t)(128 + ks * 32 + kg * 8 + j) * HID + col]);
            bwh[n][ks] = wh;
        }
        if (kg == 0) bias_lds[g * 128 + col] = bsel[col];
    }

    if (tid < 128) ((unsigned*)h_bf)[tid] = 0u;   // h0 = 0

    // cell geometry (waves 0-3)
    const int crow = wid >> 1;               // 0,0,1,1
    const int ccol = (wid & 1) * 64 + lane;
    float c_reg = 0.f, h_last = 0.f;         // c0 = 0
    const int c_act = cb + lane;             // Phase-A activation col (lane order)

    // x staging geometry (waves 4-7; pt 0..255): 1 float4/lane  (R18 verbatim)
    const int pt = tid - 256;
    const int sm = (pt >> 5) & 7;            // window row m = 2*step+brow
    const int sc = pt & 31;                  // 4-float chunk
    const size_t xrow_off = ((size_t)(b0 + (sm & 1))) * HID + sc * 4;
    const int xw_boff = sm * 256 + ((((sc >> 1) ^ (sm & 7)) << 4) | ((sc & 1) << 3));

#define STAGE_XWIN(buf, s0) do {                                                    \
    const float* xp_ = X + ((size_t)((s0) + (sm >> 1)) * BATCH) * HID + xrow_off;   \
    float4v a_ = *(const float4v*)xp_;                                              \
    ushort4v o_;                                                                    \
    o_[0] = f2bf(a_[0]); o_[1] = f2bf(a_[1]); o_[2] = f2bf(a_[2]); o_[3] = f2bf(a_[3]); \
    *(ushort4v*)((char*)&x_win[buf][0][0] + xw_boff) = o_;                          \
} while (0)

// XT2(i, bn, buf): executed by waves 4-7 (gate v = wid-4). Both col-half
// units of gate v, tile i, window at bn. ax frags shared between units.
// D reg j of lane(kg,l15): step kg*2+(j>>1), row j&1 (valid kg<2).
// (R18-verified XTILE mappings; bias from bias_lds.)
#define XT2(i, bn, buf) do {                                                        \
    short8v axk[4];                                                                 \
    _Pragma("unroll")                                                               \
    for (int ks_ = 0; ks_ < 4; ++ks_)                                               \
        axk[ks_] = *(const short8v*)((const char*)&x_win[buf][0][0] +               \
            ((l15 & 7) * 256 + (((ks_ * 4 + kg) ^ (l15 & 7)) << 4)));               \
    _Pragma("unroll")                                                               \
    for (int uh_ = 0; uh_ < 2; ++uh_) {                                             \
        const int u_  = (wid - 4) * 2 + uh_;                                        \
        const int cs_ = uh_ * 64 + (i) * 16 + l15;                                  \
        const float bb_ = bias_lds[(wid - 4) * 128 + cs_];                          \
        float4v xa_; xa_[0] = bb_; xa_[1] = bb_; xa_[2] = bb_; xa_[3] = bb_;        \
        _Pragma("unroll")                                                           \
        for (int ks_ = 0; ks_ < 4; ++ks_)                                           \
            xa_ = __builtin_amdgcn_mfma_f32_16x16x32_bf16(axk[ks_],                 \
                      wx_lds[u_][i][ks_][lane], xa_, 0, 0, 0);                      \
        if (kg < 2) {                                                               \
            zr_lds[zswz(((bn) + kg * 2) & 7,     wid - 4, cs_)] = packbf(xa_[0], xa_[1]); \
            zr_lds[zswz(((bn) + kg * 2 + 1) & 7, wid - 4, cs_)] = packbf(xa_[2], xa_[3]); \
        }                                                                           \
    }                                                                               \
} while (0)

    // ---- prologue C: stage x_win[0]<-x[0..3], x_win[1]<-x[4..7] ----
    if (wid >= 4) { STAGE_XWIN(0, 0); STAGE_XWIN(1, 4); }
    BAR();
    // ---- prologue D: produce zring window 0 (slots 0-3), waves 4-7 ----
    if (wid >= 4) {
        XT2(0, 0, 0);
        XT2(1, 0, 0);
        XT2(2, 0, 0);
        XT2(3, 0, 0);
    }
    BAR();

    float4v xg = {};   // staged x (waves 4-7; issued w==0 Phase A, published w==2 Phase B)

    #pragma unroll 1
    for (int t = 0; t < SEQ; ++t) {
        const int w = t & 3;
        const int W = t >> 2;
        const int bnext = (t & ~3) + 4;

        // ---------------- Phase A (all 8 waves) ----------------
        const unsigned zp = zr_lds[zswz(t & 7, g, c_act)];   // early z read
        short8v ah[4];
        #pragma unroll
        for (int ks = 0; ks < 4; ++ks)
            ah[ks] = *(const short8v*)&h_bf[l15 & 1][ks * 32 + kg * 8];

        if (w == 0 && wid >= 4 && bnext + 4 < SEQ)
            xg = *(const float4v*)(X + ((size_t)(bnext + 4 + (sm >> 1)) * BATCH) * HID + xrow_off);

        // h-GEMM: 16 MFMA (4 tiles x 4 ks), rows replicated in M
        float4v acc[4];
        #pragma unroll
        for (int n = 0; n < 4; ++n)
            #pragma unroll
            for (int j = 0; j < 4; ++j) acc[n][j] = 0.f;
        __builtin_amdgcn_s_setprio(1);
        #pragma unroll
        for (int ks = 0; ks < 4; ++ks)
            #pragma unroll
            for (int n = 0; n < 4; ++n)
                acc[n] = __builtin_amdgcn_mfma_f32_16x16x32_bf16(ah[ks], bwh[n][ks], acc[n], 0, 0, 0);
        __builtin_amdgcn_s_setprio(0);

        // extract this lane's col (tile kg, col c_act), rows = reg 0/1
        float s0 = ((kg == 0) ? acc[0][0] : (kg == 1) ? acc[1][0]
                  : (kg == 2) ? acc[2][0] : acc[3][0]) + bf2f((unsigned short)(zp & 0xffffu));
        float s1 = ((kg == 0) ? acc[0][1] : (kg == 1) ? acc[1][1]
                  : (kg == 2) ? acc[2][1] : acc[3][1]) + bf2f((unsigned short)(zp >> 16));

        float v0, v1;
        if (g == 0) {
            // inclusive cumprod of cos over this half's 64 cols (lane order)
            float S0 = fast_cos(s0), S1 = fast_cos(s1);
            S0 *= dpp1<0x111, 0xf>(S0);  S1 *= dpp1<0x111, 0xf>(S1);
            S0 *= dpp1<0x112, 0xf>(S0);  S1 *= dpp1<0x112, 0xf>(S1);
            S0 *= dpp1<0x114, 0xf>(S0);  S1 *= dpp1<0x114, 0xf>(S1);
            S0 *= dpp1<0x118, 0xf>(S0);  S1 *= dpp1<0x118, 0xf>(S1);
            const float T00 = __shfl(S0, 15), T01 = __shfl(S0, 31), T02 = __shfl(S0, 47);
            const float T10 = __shfl(S1, 15), T11 = __shfl(S1, 31), T12 = __shfl(S1, 47);
            const float rp0 = (kg == 0) ? 1.f : (kg == 1) ? T00
                            : (kg == 2) ? T00 * T01 : T00 * T01 * T02;
            const float rp1 = (kg == 0) ? 1.f : (kg == 1) ? T10
                            : (kg == 2) ? T10 * T11 : T10 * T11 * T12;
            v0 = rp0 * S0;                 // raw inclusive; final f made in Phase B
            v1 = rp1 * S1;
            if (wid == 0 && lane == 63) { scanT[0] = v0; scanT[1] = v1; }
        } else if (g == 1) {
            v0 = (fast_cos(s0) + 1.f) * .5f;
            v1 = (fast_cos(s1) + 1.f) * .5f;
        } else if (g == 2) {
            v0 = fast_tanh(s0);
            v1 = fast_tanh(s1);
        } else {
            v0 = fast_sigmoid(s0);
            v1 = fast_sigmoid(s1);
        }
        ga_lds[gswz(0, g, c_act)] = v0;
        ga_lds[gswz(1, g, c_act)] = v1;

        BAR();  // S1: gact + scanT published

        // ---------------- Phase B ----------------
        if (wid < 4) {
            float fv = ga_lds[gswz(crow, 0, ccol)];
            if (wid & 1) fv *= scanT[crow];              // cross-half cumprod fixup
            const float f  = (fv + 1.f) * 0.5f;
            const float iv = ga_lds[gswz(crow, 1, ccol)];
            const float gv = ga_lds[gswz(crow, 2, ccol)];
            const float ov = ga_lds[gswz(crow, 3, ccol)];
            const float cn = fmaf(f, c_reg, iv * gv);
            const float hn = ov * fast_tanh(cn);
            c_reg = cn; h_last = hn;
            h_bf[crow][ccol] = f2bf(hn);
            out[((size_t)t * BATCH + b0 + crow) * HID + ccol] = hn;
        } else {
            // x-GEMM for next window: gate (wid-4), tile w, both halves.
            if (bnext < SEQ) {
                const int xbuf = (W + 1) & 1;
                switch (w) {
                    case 0: XT2(0, bnext, xbuf); break;
                    case 1: XT2(1, bnext, xbuf); break;
                    case 2: XT2(2, bnext, xbuf); break;
                    default: XT2(3, bnext, xbuf); break;
                }
            }
            if (w == 2 && bnext + 4 < SEQ) {
                // publish staged x (issued w==0) for window W+2 into buf W&1
                ushort4v o_;
                o_[0] = f2bf(xg[0]); o_[1] = f2bf(xg[1]); o_[2] = f2bf(xg[2]); o_[3] = f2bf(xg[3]);
                *(ushort4v*)((char*)&x_win[W & 1][0][0] + xw_boff) = o_;
            }
        }
        BAR();  // S2: h_bf + zring window tiles + x_win ready
    }

    // final hx/cx tails (waves 0-3 hold their (row,col) last-step values)
    if (wid < 4) {
        const size_t base = (size_t)SEQ * BATCH * HID;
        const size_t ro = (size_t)(b0 + crow) * HID + ccol;
        out[base + ro] = h_last;
        out[base + (size_t)BATCH * HID + ro] = c_reg;
    }
#undef STAGE_XWIN
#undef XT2
}

// ---------------------------------------------------------------------------
extern "C" void kernel_launch(void* const* d_in, const int* in_sizes, int n_in,
                              void* d_out, int out_size, void* d_ws, size_t ws_size,
                              hipStream_t stream) {
    const float* X  = (const float*)d_in[0];
    const float* Wf = (const float*)d_in[1];
    const float* bf = (const float*)d_in[2];
    const float* Wi = (const float*)d_in[3];
    const float* bi = (const float*)d_in[4];
    const float* Wg = (const float*)d_in[5];
    const float* bg = (const float*)d_in[6];
    const float* Wo = (const float*)d_in[7];
    const float* bo = (const float*)d_in[8];
    float* out = (float*)d_out;
    (void)d_ws; (void)ws_size;

    qlstm_fused<<<BATCH / 2, 512, 0, stream>>>(
        X, Wf, bf, Wi, bi, Wg, bg, Wo, bo, out);
}

// Round 21
// 1067.524 us; speedup vs baseline: 1.1489x; 1.1186x over previous
//
#include <hip/hip_runtime.h>

#define SEQ   1024
#define BATCH 512
#define HID   128

typedef __attribute__((ext_vector_type(8))) short          short8v;
typedef __attribute__((ext_vector_type(4))) float          float4v;
typedef __attribute__((ext_vector_type(8))) unsigned short ushort8v;

__device__ __forceinline__ unsigned short f2bf(float f) {
    union { float f; unsigned u; } v; v.f = f;
    return (unsigned short)((v.u + 0x7fffu + ((v.u >> 16) & 1u)) >> 16);
}
__device__ __forceinline__ float bf2f(unsigned short u) {
    union { unsigned u; float f; } v; v.u = ((unsigned)u) << 16;
    return v.f;
}
__device__ __forceinline__ unsigned packbf(float a, float b) {
    return (unsigned)f2bf(a) | ((unsigned)f2bf(b) << 16);
}
__device__ __forceinline__ float fast_cos(float x) {
    return __builtin_amdgcn_cosf(x * 0.15915494309189535f);   // v_cos takes revolutions
}
__device__ __forceinline__ float fast_sigmoid(float x) {
    return __builtin_amdgcn_rcpf(1.0f + __builtin_amdgcn_exp2f(-1.4426950408889634f * x));
}
__device__ __forceinline__ float fast_tanh(float x) {
    return 1.0f - 2.0f * __builtin_amdgcn_rcpf(1.0f + __builtin_amdgcn_exp2f(2.8853900817779268f * x));
}
template<int CTRL, int RM>
__device__ __forceinline__ float dpp1(float v) {
    union { float f; int i; } s, o, r;
    s.f = v; o.f = 1.0f;
    r.i = __builtin_amdgcn_update_dpp(o.i, s.i, CTRL, RM, 0xf, false);
    return r.f;
}
#define BAR() do { asm volatile("s_waitcnt lgkmcnt(0)" ::: "memory");  \
                   __builtin_amdgcn_s_barrier();                       \
                   __builtin_amdgcn_sched_barrier(0); } while (0)

// in-wave inclusive cumprod over 128 cols held as (a = col kg*32+l15,
// b = col kg*32+16+l15). 16-lane DPP scans + block totals via shfl. (R12-verified)
__device__ __forceinline__ void fscan(float a, float b, int kg,
                                      float& Fa, float& Fb) {
    float Sa = a, Sb = b;
    Sa *= dpp1<0x111, 0xf>(Sa);  Sb *= dpp1<0x111, 0xf>(Sb);   // row_shr:1
    Sa *= dpp1<0x112, 0xf>(Sa);  Sb *= dpp1<0x112, 0xf>(Sb);   // row_shr:2
    Sa *= dpp1<0x114, 0xf>(Sa);  Sb *= dpp1<0x114, 0xf>(Sb);   // row_shr:4
    Sa *= dpp1<0x118, 0xf>(Sa);  Sb *= dpp1<0x118, 0xf>(Sb);   // row_shr:8
    const float T0a = __shfl(Sa, 15), T0b = __shfl(Sb, 15);
    const float T1a = __shfl(Sa, 31), T1b = __shfl(Sb, 31);
    const float T2a = __shfl(Sa, 47), T2b = __shfl(Sb, 47);
    const float Taown = __shfl(Sa, kg * 16 + 15);
    const float p0 = T0a * T0b, p1 = T1a * T1b, p2 = T2a * T2b;
    const float rp = (kg == 0) ? 1.f : (kg == 1) ? p0
                   : (kg == 2) ? p0 * p1 : p0 * p1 * p2;
    Fa = rp * Sa;
    Fb = rp * Taown * Sb;
}

// LDS swizzles (R13-verified): bijective in col; hot accesses <=2-way.
__device__ __forceinline__ int zswz(int slot, int g, int c) {
    return slot * 512 + g * 128 + (c ^ ((c >> 5) << 4) ^ ((slot & 2) << 3));
}
__device__ __forceinline__ int gswz(int row, int g, int c) {
    return row * 512 + g * 128 + (c ^ ((c >> 5) << 4));
}

// ---------------------------------------------------------------------------
// ONE persistent kernel. 256 WGs x 512 thr (8 waves, 2/SIMD), 2 rows/WG, 1 WG/CU.
// Waves 0-3 CONSUMERS (gate g=wid): h-GEMM (rows replicated in M, W_h in regs,
//   z from bf16 ring) + in-register activation (wave0 = full fscan) -> gact.
// Waves 4-7 PRODUCERS (gate g=wid-4): x-window GEMM — 16 M-slots = 8 steps x
//   2 rows, ONE 4-MFMA tile per step (amortized 4 MFMA/step).
//   ax frags reloaded once per window (w==0); x staged global->reg (w==0) ->
//   x_win (w==4, Phase B). All mappings R13-refcheck'd.
// Phase A: consumer MFMA (setprio) + act  ||  producer tile; S1.
// Phase B: consumer cell update (1 (row,col)/lane, 4 waves)  ||  wave-4 x_win
//   publish; S2.
// (R14 champion kernel, restored verbatim: 1040 us, VGPR 128, no spill.)
// ---------------------------------------------------------------------------
__global__ __launch_bounds__(512, 1) void qlstm_fused(
    const float* __restrict__ X,
    const float* __restrict__ Wf, const float* __restrict__ bfp,
    const float* __restrict__ Wi, const float* __restrict__ bip,
    const float* __restrict__ Wg, const float* __restrict__ bgp,
    const float* __restrict__ Wo, const float* __restrict__ bop,
    float* __restrict__ out)
{
    __shared__ unsigned zr_lds[16 * 4 * 128];                 // 32 KB bf16 row-pair z ring
    __shared__ float    ga_lds[2 * 4 * 128];                  // 4 KB activated gates
    __shared__ alignas(8)  unsigned short h_bf[2][HID];       // 512 B
    __shared__ alignas(16) unsigned short x_win[2][16][HID];  // 8 KB x window dbuf

    const int tid = threadIdx.x, lane = tid & 63, wid = tid >> 6;
    const int l15 = lane & 15, kg = lane >> 4;
    const int b0 = blockIdx.x * 2;
    const bool prod = (wid >= 4);
    const int g = wid & 3;
    const float* Wsel = (g == 0) ? Wf : (g == 1) ? Wi : (g == 2) ? Wg : Wo;
    const float* bsel = (g == 0) ? bfp : (g == 1) ? bip : (g == 2) ? bgp : bop;

    // ONE weight set per wave: consumers W_h (k 128..255), producers W_x (k 0..127)
    short8v bw[8][4];
    {
        const int kbase = prod ? 0 : 128;
        #pragma unroll
        for (int n = 0; n < 8; ++n) {
            const int col = n * 16 + l15;
            #pragma unroll
            for (int ks = 0; ks < 4; ++ks) {
                const int k0 = kbase + ks * 32 + kg * 8;
                short8v a;
                #pragma unroll
                for (int j = 0; j < 8; ++j)
                    a[j] = (short)f2bf(Wsel[(size_t)(k0 + j) * HID + col]);
                bw[n][ks] = a;
            }
        }
    }
    float biasr[8];
    #pragma unroll
    for (int n = 0; n < 8; ++n) biasr[n] = prod ? bsel[n * 16 + l15] : 0.f;

    if (tid < 128) ((unsigned*)h_bf)[tid] = 0u;   // h0 = 0

    // consumer Phase-B cell geometry (1 (row,col)/lane across waves 0-3)
    const int crow = wid >> 1;
    const int ccol = (wid & 1) * 64 + lane;
    const int ca0  = kg * 32 + l15;
    float c_reg = 0.f, h_last = 0.f;

    // producer x_win staging geometry (256 producer threads): row m = 2*step+row
    const int pt  = tid - 256;                 // 0..255 for producers
    const int sm  = (pt >> 4) & 15;            // m 0..15
    const int sbl = pt & 15;                   // 16B block
    const size_t xrow_off = ((size_t)(b0 + (sm & 1))) * HID + sbl * 8;
    const int xw_off = (sbl * 16) ^ ((sm & 7) << 4);
    const int xsw = (l15 & 7) << 4;

#define STAGE_XWIN(buf, s0) do {                                                   \
    const float* xp_ = X + ((size_t)((s0) + (sm >> 1)) * BATCH) * HID + xrow_off;  \
    float4v a_ = *(const float4v*)xp_;                                             \
    float4v b_ = *(const float4v*)(xp_ + 4);                                       \
    ushort8v o_;                                                                   \
    o_[0]=f2bf(a_[0]); o_[1]=f2bf(a_[1]); o_[2]=f2bf(a_[2]); o_[3]=f2bf(a_[3]);    \
    o_[4]=f2bf(b_[0]); o_[5]=f2bf(b_[1]); o_[6]=f2bf(b_[2]); o_[7]=f2bf(b_[3]);    \
    *(ushort8v*)((char*)&x_win[buf][sm][0] + xw_off) = o_;                         \
} while (0)

#define LOAD_AX(buf) do {                                                          \
    const char* xb_ = (const char*)&x_win[buf][0][0] + l15 * 256;                  \
    ax[0] = *(const short8v*)(xb_ + ((      kg * 16) ^ xsw));                      \
    ax[1] = *(const short8v*)(xb_ + (( 64 + kg * 16) ^ xsw));                      \
    ax[2] = *(const short8v*)(xb_ + ((128 + kg * 16) ^ xsw));                      \
    ax[3] = *(const short8v*)(xb_ + ((192 + kg * 16) ^ xsw));                      \
} while (0)

// 4-MFMA x-tile N of next window; lane(kg,l15) reg j -> step kg*2+(j>>1),
// row j&1, col N*16+l15. (R13-verified mapping)
#define XTILE(N) do {                                                              \
    float4v xa_;                                                                   \
    xa_[0] = biasr[N]; xa_[1] = biasr[N]; xa_[2] = biasr[N]; xa_[3] = biasr[N];    \
    xa_ = __builtin_amdgcn_mfma_f32_16x16x32_bf16(ax[0], bw[N][0], xa_, 0, 0, 0);  \
    xa_ = __builtin_amdgcn_mfma_f32_16x16x32_bf16(ax[1], bw[N][1], xa_, 0, 0, 0);  \
    xa_ = __builtin_amdgcn_mfma_f32_16x16x32_bf16(ax[2], bw[N][2], xa_, 0, 0, 0);  \
    xa_ = __builtin_amdgcn_mfma_f32_16x16x32_bf16(ax[3], bw[N][3], xa_, 0, 0, 0);  \
    const int se_ = (bnext + kg * 2) & 15;                                         \
    const int cs_ = (N) * 16 + l15;                                                \
    zr_lds[zswz(se_,     g, cs_)] = packbf(xa_[0], xa_[1]);                        \
    zr_lds[zswz(se_ + 1, g, cs_)] = packbf(xa_[2], xa_[3]);                        \
} while (0)

    short8v ax[4] = {};           // producer: current-window x A-frags
    float4v xg0 = {}, xg1 = {};   // producer: staged x (issued w==0, written w==4)

    // ---- prologue: x_win[0]<-x[0..7], x_win[1]<-x[8..15]; z slots 0..7 ----
    if (prod) { STAGE_XWIN(0, 0); STAGE_XWIN(1, 8); }
    BAR();
    if (prod) {
        LOAD_AX(0);
        float4v pacc[8];
        #pragma unroll
        for (int n = 0; n < 8; ++n)
            #pragma unroll
            for (int j = 0; j < 4; ++j) pacc[n][j] = biasr[n];
        #pragma unroll
        for (int ks = 0; ks < 4; ++ks)
            #pragma unroll
            for (int n = 0; n < 8; ++n)
                pacc[n] = __builtin_amdgcn_mfma_f32_16x16x32_bf16(ax[ks], bw[n][ks], pacc[n], 0, 0, 0);
        #pragma unroll
        for (int n = 0; n < 8; ++n) {
            const int se_ = kg * 2;
            const int cs_ = n * 16 + l15;
            zr_lds[zswz(se_,     g, cs_)] = packbf(pacc[n][0], pacc[n][1]);
            zr_lds[zswz(se_ + 1, g, cs_)] = packbf(pacc[n][2], pacc[n][3]);
        }
    }
    BAR();

    #pragma unroll 1
    for (int t = 0; t < SEQ; ++t) {
        const int w = t & 7;
        const int W = t >> 3;
        const int bnext = (t & ~7) + 8;

        // ---------------- Phase A ----------------
        if (!prod) {
            // early LDS reads (latency hides under MFMA burst)
            const unsigned zp0 = zr_lds[zswz(t & 15, g, ca0)];
            const unsigned zp1 = zr_lds[zswz(t & 15, g, ca0 + 16)];
            short8v ah[4];
            #pragma unroll
            for (int ks = 0; ks < 4; ++ks)
                ah[ks] = *(const short8v*)&h_bf[l15 & 1][ks * 32 + kg * 8];

            float4v acc[8];
            #pragma unroll
            for (int n = 0; n < 8; ++n)
                #pragma unroll
                for (int j = 0; j < 4; ++j) acc[n][j] = 0.f;

            __builtin_amdgcn_s_setprio(1);
            #pragma unroll
            for (int ks = 0; ks < 4; ++ks)
                #pragma unroll
                for (int n = 0; n < 8; ++n)
                    acc[n] = __builtin_amdgcn_mfma_f32_16x16x32_bf16(ah[ks], bw[n][ks], acc[n], 0, 0, 0);
            __builtin_amdgcn_s_setprio(0);

            // tiles n=2kg,2kg+1; reg parity = batch row
            float s0r0 = ((kg == 0) ? acc[0][0] : (kg == 1) ? acc[2][0]
                        : (kg == 2) ? acc[4][0] : acc[6][0]) + bf2f((unsigned short)(zp0 & 0xffffu));
            float s0r1 = ((kg == 0) ? acc[0][1] : (kg == 1) ? acc[2][1]
                        : (kg == 2) ? acc[4][1] : acc[6][1]) + bf2f((unsigned short)(zp0 >> 16));
            float s1r0 = ((kg == 0) ? acc[1][0] : (kg == 1) ? acc[3][0]
                        : (kg == 2) ? acc[5][0] : acc[7][0]) + bf2f((unsigned short)(zp1 & 0xffffu));
            float s1r1 = ((kg == 0) ? acc[1][1] : (kg == 1) ? acc[3][1]
                        : (kg == 2) ? acc[5][1] : acc[7][1]) + bf2f((unsigned short)(zp1 >> 16));

            float v00, v01, v10, v11;
            if (g == 0) {
                float Fa0, Fb0, Fa1, Fb1;
                fscan(fast_cos(s0r0), fast_cos(s1r0), kg, Fa0, Fb0);
                fscan(fast_cos(s0r1), fast_cos(s1r1), kg, Fa1, Fb1);
                v00 = (Fa0 + 1.f) * 0.5f; v01 = (Fb0 + 1.f) * 0.5f;
                v10 = (Fa1 + 1.f) * 0.5f; v11 = (Fb1 + 1.f) * 0.5f;
            } else if (g == 1) {
                v00 = (fast_cos(s0r0) + 1.f) * .5f; v01 = (fast_cos(s1r0) + 1.f) * .5f;
                v10 = (fast_cos(s0r1) + 1.f) * .5f; v11 = (fast_cos(s1r1) + 1.f) * .5f;
            } else if (g == 2) {
                v00 = fast_tanh(s0r0); v01 = fast_tanh(s1r0);
                v10 = fast_tanh(s0r1); v11 = fast_tanh(s1r1);
            } else {
                v00 = fast_sigmoid(s0r0); v01 = fast_sigmoid(s1r0);
                v10 = fast_sigmoid(s0r1); v11 = fast_sigmoid(s1r1);
            }
            ga_lds[gswz(0, g, ca0)]      = v00;
            ga_lds[gswz(0, g, ca0 + 16)] = v01;
            ga_lds[gswz(1, g, ca0)]      = v10;
            ga_lds[gswz(1, g, ca0 + 16)] = v11;
        } else {
            if (w == 0) {
                if (bnext < SEQ) LOAD_AX((W + 1) & 1);
                if (bnext + 8 < SEQ) {   // issue global x loads (consumed w==4)
                    const float* xp = X + ((size_t)(bnext + 8 + (sm >> 1)) * BATCH) * HID + xrow_off;
                    xg0 = *(const float4v*)xp;
                    xg1 = *(const float4v*)(xp + 4);
                }
            }
            if (bnext < SEQ) {           // one 4-MFMA tile of next window
                switch (w) {
                    case 0: XTILE(0); break;
                    case 1: XTILE(1); break;
                    case 2: XTILE(2); break;
                    case 3: XTILE(3); break;
                    case 4: XTILE(4); break;
                    case 5: XTILE(5); break;
                    case 6: XTILE(6); break;
                    default: XTILE(7); break;
                }
            }
        }
        BAR();  // S1: gact + zring tile published

        // ---------------- Phase B ----------------
        if (!prod) {
            const float fv = ga_lds[gswz(crow, 0, ccol)];
            const float iv = ga_lds[gswz(crow, 1, ccol)];
            const float gv = ga_lds[gswz(crow, 2, ccol)];
            const float ov = ga_lds[gswz(crow, 3, ccol)];
            const float cn = fmaf(fv, c_reg, iv * gv);
            const float hn = ov * fast_tanh(cn);
            c_reg = cn; h_last = hn;
            h_bf[crow][ccol] = f2bf(hn);
            out[((size_t)t * BATCH + b0 + crow) * HID + ccol] = hn;
        } else if (w == 4 && bnext + 8 < SEQ) {
            // publish staged x (loaded at w==0) for window W+2
            ushort8v o_;
            o_[0]=f2bf(xg0[0]); o_[1]=f2bf(xg0[1]); o_[2]=f2bf(xg0[2]); o_[3]=f2bf(xg0[3]);
            o_[4]=f2bf(xg1[0]); o_[5]=f2bf(xg1[1]); o_[6]=f2bf(xg1[2]); o_[7]=f2bf(xg1[3]);
            *(ushort8v*)((char*)&x_win[W & 1][sm][0] + xw_off) = o_;
        }
        BAR();  // S2: h_bf (and x_win) ready
    }

    // final hx/cx tails (consumer lanes hold their (row,col) last-step values)
    if (!prod) {
        const size_t base = (size_t)SEQ * BATCH * HID;
        const size_t ro = (size_t)(b0 + crow) * HID + ccol;
        out[base + ro] = h_last;
        out[base + (size_t)BATCH * HID + ro] = c_reg;
    }
#undef STAGE_XWIN
#undef LOAD_AX
#undef XTILE
}

// ---------------------------------------------------------------------------
extern "C" void kernel_launch(void* const* d_in, const int* in_sizes, int n_in,
                              void* d_out, int out_size, void* d_ws, size_t ws_size,
                              hipStream_t stream) {
    const float* X  = (const float*)d_in[0];
    const float* Wf = (const float*)d_in[1];
    const float* bf = (const float*)d_in[2];
    const float* Wi = (const float*)d_in[3];
    const float* bi = (const float*)d_in[4];
    const float* Wg = (const float*)d_in[5];
    const float* bg = (const float*)d_in[6];
    const float* Wo = (const float*)d_in[7];
    const float* bo = (const float*)d_in[8];
    float* out = (float*)d_out;
    (void)d_ws; (void)ws_size;

    qlstm_fused<<<BATCH / 2, 512, 0, stream>>>(
        X, Wf, bf, Wi, bi, Wg, bg, Wo, bo, out);
}